// Round 3
// baseline (2301.122 us; speedup 1.0000x reference)
//
#include <hip/hip_runtime.h>
#include <hip/hip_bf16.h>
#include <stdint.h>

// SparseMPNNLayer: bipartite MPNN, H=64. Round 4 (resubmit — R2 bench was an
// infra GPUAcquisitionTimeout, no signal): MFMA edge MLP.
//  Edge MLP (192->128->64) per 32-edge wave as two GEMMs on v_mfma_f32_16x16x32_bf16:
//   layer1: X(32x192) x W1(192x128), A-frags gathered straight from global (x is bf16
//           when flag=1), W1 pre-packed on device into fragment order, SPLIT hi+lo bf16
//           (w = hi + lo) -> 2 MFMA passes = ~f32 precision.
//   layer2: OUT^T = W2^T x H^T. H round-trips through LDS pre-split into hi/lo bf16;
//           3 MFMA passes (hi*hi + hi*lo + lo*hi).
//  Epilogue: LDS transpose -> coalesced row-wise atomicAdd (unchanged pattern).
//  f32-storage path keeps the round-3 VALU kernel (flag-gated dead launch).
//  Issue count: 288 MFMA/wave vs 32768 VALU FMA -> no longer issue-starved at 2 waves/SIMD.

typedef __attribute__((ext_vector_type(8))) short short8v;   // 8 bf16 (4 VGPRs)
typedef __attribute__((ext_vector_type(4))) float f32x4;

__device__ __forceinline__ ushort f2bf_rn(float f) {
    union { float f; unsigned int u; } v; v.f = f;
    unsigned int u = v.u;
    unsigned int r = u + 0x7fffu + ((u >> 16) & 1u);   // round-to-nearest-even
    return (ushort)(r >> 16);
}
__device__ __forceinline__ float bf2f(ushort h) {
    union { unsigned int u; float f; } v; v.u = ((unsigned int)h) << 16;
    return v.f;
}

__device__ __forceinline__ void unpack2(unsigned int u, float& a, float& b) {
    union { unsigned int i; float f; } x, y;
    x.i = u << 16;
    y.i = u & 0xffff0000u;
    a = x.f; b = y.f;
}

__device__ __forceinline__ void load16bf(const __hip_bfloat16* __restrict__ p, float* xr) {
    const uint4* q = reinterpret_cast<const uint4*>(p);
    uint4 a = q[0];
    uint4 b = q[1];
    unpack2(a.x, xr[0], xr[1]);  unpack2(a.y, xr[2], xr[3]);
    unpack2(a.z, xr[4], xr[5]);  unpack2(a.w, xr[6], xr[7]);
    unpack2(b.x, xr[8], xr[9]);  unpack2(b.y, xr[10], xr[11]);
    unpack2(b.z, xr[12], xr[13]); unpack2(b.w, xr[14], xr[15]);
}

__device__ __forceinline__ void load16f(const float* __restrict__ p, float* xr) {
    const float4* q = reinterpret_cast<const float4*>(p);
#pragma unroll
    for (int i = 0; i < 4; ++i) {
        float4 v = q[i];
        xr[4*i+0] = v.x; xr[4*i+1] = v.y; xr[4*i+2] = v.z; xr[4*i+3] = v.w;
    }
}

__device__ __forceinline__ void load16(const void* base, size_t off, int isbf, float* xr) {
    if (isbf) load16bf((const __hip_bfloat16*)base + off, xr);
    else      load16f((const float*)base + off, xr);
}

// Classify storage of h_v: packed-bf16 pairs have a bf16 exponent field in the
// low 16 bits of each u32 (~99.7% in [100,140] for N(0,1)); f32 mantissa bits
// hit that window ~16% of the time.
__global__ void detect_kernel(const unsigned int* __restrict__ hv, int* __restrict__ flag) {
    __shared__ int cnt;
    if (threadIdx.x == 0) cnt = 0;
    __syncthreads();
    unsigned int w = hv[threadIdx.x];
    int ef = (w >> 7) & 0xff;
    if (ef >= 100 && ef <= 140) atomicAdd(&cnt, 1);
    __syncthreads();
    if (threadIdx.x == 0) flag[0] = (cnt > 256) ? 1 : 0;
}

struct WArgs {
    const void* p[16];
    int off[16];
    int cnt[16];
};

__global__ void cvt_all(WArgs wa, float* __restrict__ wf, const int* __restrict__ gflag) {
    const int isbf = gflag[0];
    const int t = blockIdx.y;
    const int i = blockIdx.x * 256 + threadIdx.x;
    if (i >= wa.cnt[t]) return;
    wf[wa.off[t] + i] = isbf ? __bfloat162float(((const __hip_bfloat16*)wa.p[t])[i])
                             : ((const float*)wa.p[t])[i];
}

// Pack W1 (f32 192x128) into MFMA B-fragment order for 16x16x32, split hi/lo bf16.
// Layout: [nt(8)][kt(6)][lane(64)][j(8)]; element = w1[(kt*32 + (lane>>4)*8 + j)*128 + nt*16 + (lane&15)]
__global__ void pack_w1(const float* __restrict__ w1, ushort* __restrict__ hi, ushort* __restrict__ lo) {
    int i = blockIdx.x * 256 + threadIdx.x;
    if (i >= 8 * 6 * 64 * 8) return;
    int j = i & 7;
    int lane = (i >> 3) & 63;
    int t = i >> 9;
    int kt = t % 6, nt = t / 6;
    float w = w1[(kt * 32 + (lane >> 4) * 8 + j) * 128 + nt * 16 + (lane & 15)];
    ushort h = f2bf_rn(w);
    hi[i] = h;
    lo[i] = f2bf_rn(w - bf2f(h));
}

// Pack W2^T (from w2 f32 128x64) into MFMA A-fragment order for 16x16x32, split hi/lo.
// Layout: [pair(4)][ot(4)][lane(64)][j(8)]; element = w2[(pair*32 + (lane>>4)*8 + j)*64 + ot*16 + (lane&15)]
__global__ void pack_w2(const float* __restrict__ w2, ushort* __restrict__ hi, ushort* __restrict__ lo) {
    int i = blockIdx.x * 256 + threadIdx.x;
    if (i >= 4 * 4 * 64 * 8) return;
    int j = i & 7;
    int lane = (i >> 3) & 63;
    int t = i >> 9;
    int ot = t & 3, pair = t >> 2;
    float w = w2[(pair * 32 + (lane >> 4) * 8 + j) * 64 + ot * 16 + (lane & 15)];
    ushort h = f2bf_rn(w);
    hi[i] = h;
    lo[i] = f2bf_rn(w - bf2f(h));
}

__global__ void deg_kernel(const int* __restrict__ src, float* __restrict__ degv, int E) {
    int e = blockIdx.x * 256 + threadIdx.x;
    if (e < E) atomicAdd(&degv[src[e]], 1.0f);
}

// ---------------- MFMA edge MLP (bf16 storage only, flag==1) ----------------
// One wave per block, 32 edges. x = [A-rows | B-rows | e_feat] (each 64 bf16).
// ph3==0: A=h_v rows idx src, B=h_u rows idx dst, scatter row = dst
// ph3==1: A=h_u_out rows idx dst, B=h_v rows idx src, scatter row = src
__global__ __launch_bounds__(64)
void edge_mlp_mfma(const void* __restrict__ A_, const void* __restrict__ B_,
                   const void* __restrict__ E_,
                   const int* __restrict__ src_idx, const int* __restrict__ dst_idx,
                   const int* __restrict__ gflag,
                   const ushort* __restrict__ w1hi, const ushort* __restrict__ w1lo,
                   const ushort* __restrict__ w2hi, const ushort* __restrict__ w2lo,
                   const float* __restrict__ b1, const float* __restrict__ b2,
                   float* __restrict__ accum, int E, int ph3) {
    if (gflag[0] != 1) return;

    __shared__ ushort hb_hi[32][40];   // H tile hi, row stride 80B (16B-aligned reads)
    __shared__ ushort hb_lo[32][40];   // H tile lo
    __shared__ float  smt[32][17];     // epilogue transpose
    __shared__ int rowS[32], gA[32], gB[32];

    const int lane = threadIdx.x;
    const int base = blockIdx.x * 32;
    const int cnt = min(32, E - base);
    const int eloc = lane & 15;            // N-dim / col lane index
    const int khalf = (lane >> 4) * 8;     // K-slice base within a K=32 tile

    if (lane < 32) {
        int e = base + ((lane < cnt) ? lane : (cnt - 1));
        int s = src_idx[e], d = dst_idx[e];
        rowS[lane] = ph3 ? s : d;
        gA[lane]   = ph3 ? d : s;
        gB[lane]   = ph3 ? s : d;
    }
    __syncthreads();

    // Gather all A-fragments: afr[kt][mt], 16B/lane each, issued up front.
    const ushort* Ab = (const ushort*)A_;
    const ushort* Bb = (const ushort*)B_;
    const ushort* Eb = (const ushort*)E_;
    short8v afr[6][2];
#pragma unroll
    for (int mt = 0; mt < 2; ++mt) {
        const int el = mt * 16 + eloc;
        const int elc = (el < cnt) ? el : (cnt - 1);
        const ushort* ra = Ab + (size_t)gA[elc] * 64;
        const ushort* rb = Bb + (size_t)gB[elc] * 64;
        const ushort* re = Eb + (size_t)(base + elc) * 64;
        afr[0][mt] = *(const short8v*)(ra + khalf);
        afr[1][mt] = *(const short8v*)(ra + 32 + khalf);
        afr[2][mt] = *(const short8v*)(rb + khalf);
        afr[3][mt] = *(const short8v*)(rb + 32 + khalf);
        afr[4][mt] = *(const short8v*)(re + khalf);
        afr[5][mt] = *(const short8v*)(re + 32 + khalf);
    }

    // acc2 = OUT^T tiles [ot(out 64/16)][et(edge 32/16)], init with b2[out] (per-message bias).
    f32x4 acc2[4][2];
#pragma unroll
    for (int ot = 0; ot < 4; ++ot)
#pragma unroll
        for (int r = 0; r < 4; ++r) {
            float bv = b2[ot * 16 + (lane >> 4) * 4 + r];
            acc2[ot][0][r] = bv;
            acc2[ot][1][r] = bv;
        }

#pragma unroll 1
    for (int pair = 0; pair < 4; ++pair) {           // 32 hidden per pair
#pragma unroll
        for (int nt2 = 0; nt2 < 2; ++nt2) {          // 16 hidden per ntile
            const int nt = pair * 2 + nt2;
            const float bv = b1[nt * 16 + eloc];
            f32x4 c1[2];
#pragma unroll
            for (int mt = 0; mt < 2; ++mt) {
                c1[mt][0] = bv; c1[mt][1] = bv; c1[mt][2] = bv; c1[mt][3] = bv;
            }
#pragma unroll
            for (int kt = 0; kt < 6; ++kt) {
                const size_t wo = (((size_t)(nt * 6 + kt)) * 64 + lane) * 8;
                const short8v bh = *(const short8v*)(w1hi + wo);
                const short8v bl = *(const short8v*)(w1lo + wo);
#pragma unroll
                for (int mt = 0; mt < 2; ++mt) {
                    c1[mt] = __builtin_amdgcn_mfma_f32_16x16x32_bf16(afr[kt][mt], bh, c1[mt], 0, 0, 0);
                    c1[mt] = __builtin_amdgcn_mfma_f32_16x16x32_bf16(afr[kt][mt], bl, c1[mt], 0, 0, 0);
                }
            }
            // relu + split f32 -> hi/lo bf16, store H^T staging (C layout: col=lane&15=hidden,
            // row=(lane>>4)*4+r=edge)
#pragma unroll
            for (int mt = 0; mt < 2; ++mt)
#pragma unroll
                for (int r = 0; r < 4; ++r) {
                    float v = fmaxf(c1[mt][r], 0.0f);
                    ushort h = f2bf_rn(v);
                    ushort l = f2bf_rn(v - bf2f(h));
                    const int er = mt * 16 + (lane >> 4) * 4 + r;
                    hb_hi[er][nt2 * 16 + eloc] = h;
                    hb_lo[er][nt2 * 16 + eloc] = l;
                }
        }
        __syncthreads();
        // layer2: OUT^T += W2^T[:, pair-hid32] x H^T[pair-hid32, :]
#pragma unroll
        for (int et = 0; et < 2; ++et) {
            const short8v bh = *(const short8v*)(&hb_hi[et * 16 + eloc][khalf]);
            const short8v bl = *(const short8v*)(&hb_lo[et * 16 + eloc][khalf]);
#pragma unroll
            for (int ot = 0; ot < 4; ++ot) {
                const size_t wo = (((size_t)(pair * 4 + ot)) * 64 + lane) * 8;
                const short8v ah = *(const short8v*)(w2hi + wo);
                const short8v al = *(const short8v*)(w2lo + wo);
                acc2[ot][et] = __builtin_amdgcn_mfma_f32_16x16x32_bf16(ah, bh, acc2[ot][et], 0, 0, 0);
                acc2[ot][et] = __builtin_amdgcn_mfma_f32_16x16x32_bf16(ah, bl, acc2[ot][et], 0, 0, 0);
                acc2[ot][et] = __builtin_amdgcn_mfma_f32_16x16x32_bf16(al, bh, acc2[ot][et], 0, 0, 0);
            }
        }
        __syncthreads();
    }

    // Epilogue: transpose OUT^T tiles through LDS -> coalesced row-wise atomics.
#pragma unroll 1
    for (int ot = 0; ot < 4; ++ot) {
        __syncthreads();
#pragma unroll
        for (int et = 0; et < 2; ++et)
#pragma unroll
            for (int r = 0; r < 4; ++r)
                smt[et * 16 + eloc][(lane >> 4) * 4 + r] = acc2[ot][et][r];
        __syncthreads();
#pragma unroll 1
        for (int i = 0; i < 32; i += 4) {
            const int e = i + (lane >> 4);
            if (e < cnt)
                atomicAdd(&accum[(size_t)rowS[e] * 64 + ot * 16 + eloc], smt[e][eloc]);
        }
    }
}

// ---------------- f32-storage fallback edge MLP (flag==0 only) ----------------
__global__ __launch_bounds__(64)
void edge_mlp(const void* __restrict__ A_f, const void* __restrict__ A_b,
              const void* __restrict__ B,
              const void* __restrict__ Efeat,
              const int* __restrict__ src_idx, const int* __restrict__ dst_idx,
              const int* __restrict__ gflag,
              const float* __restrict__ w1, const float* __restrict__ b1,
              const float* __restrict__ w2, const float* __restrict__ b2,
              float* __restrict__ accum, int E, int ph3) {
    if (gflag[0] != 0) return;
    const void* A = A_f;
    __shared__ float sm[64][17];
    __shared__ int rowS[64];

    const int lane = threadIdx.x;
    const int base = blockIdx.x * 64;
    const int cnt = min(64, E - base);
    const int eSafe = base + ((lane < cnt) ? lane : 0);
    const int s = src_idx[eSafe];
    const int d = dst_idx[eSafe];
    rowS[lane] = ph3 ? s : d;

    const size_t offA = (size_t)(ph3 ? d : s) * 64;
    const size_t offB = (size_t)(ph3 ? s : d) * 64;
    const size_t offE = (size_t)eSafe * 64;

    float acc[64];
#pragma unroll
    for (int o = 0; o < 64; ++o) acc[o] = b2[o];

#pragma unroll 1
    for (int half = 0; half < 2; ++half) {
        const int hb = half << 6;
        float h[64];
#pragma unroll
        for (int j = 0; j < 64; ++j) h[j] = b1[hb + j];
#pragma unroll 1
        for (int kc = 0; kc < 12; ++kc) {
            float xr[16];
            if (kc < 4)      load16(A, offA + kc * 16, 0, xr);
            else if (kc < 8) load16(B, offB + (kc - 4) * 16, 0, xr);
            else             load16(Efeat, offE + (kc - 8) * 16, 0, xr);
            const float* wrow = w1 + (size_t)(kc * 16) * 128 + hb;
#pragma unroll
            for (int k = 0; k < 16; ++k)
#pragma unroll
                for (int j = 0; j < 64; ++j)
                    h[j] = fmaf(xr[k], wrow[k * 128 + j], h[j]);
        }
#pragma unroll
        for (int j = 0; j < 64; ++j) h[j] = fmaxf(h[j], 0.0f);
        const float* w2h = w2 + (size_t)hb * 64;
#pragma unroll
        for (int j = 0; j < 64; ++j)
#pragma unroll
            for (int o = 0; o < 64; ++o)
                acc[o] = fmaf(h[j], w2h[j * 64 + o], acc[o]);
    }

    const int r4 = lane >> 4;
    const int c16 = lane & 15;
#pragma unroll
    for (int oc = 0; oc < 4; ++oc) {
        __syncthreads();
#pragma unroll
        for (int j = 0; j < 16; ++j) sm[lane][j] = acc[oc * 16 + j];
        __syncthreads();
        for (int i = 0; i < 64; i += 4) {
            const int e = i + r4;
            if (e < cnt)
                atomicAdd(&accum[(size_t)rowS[e] * 64 + oc * 16 + c16], sm[e][c16]);
        }
    }
}

// Node MLP: K=128 -> 64 (relu) -> 64. Full h[64] in regs -> x loaded once.
__global__ __launch_bounds__(256)
void node_mlp(const void* __restrict__ hin,
              const float* __restrict__ m,
              const float* __restrict__ degv,
              const int* __restrict__ Sptr,
              const int* __restrict__ gflag,
              const float* __restrict__ w1, const float* __restrict__ b1,
              const float* __restrict__ w2, const float* __restrict__ b2,
              void* __restrict__ out_f, void* __restrict__ out_b,
              int N, int ph4) {
    const int isbf = gflag[0];
    const int n = blockIdx.x * 256 + threadIdx.x;
    if (n >= N) return;
    const float scale = ph4 ? (1.0f / fmaxf(degv[n], 1.0f))
                            : (1.0f / (float)Sptr[0]);
    const size_t offH = (size_t)n * 64;
    const float* pm = m + offH;

    float h[64];
#pragma unroll
    for (int j = 0; j < 64; ++j) h[j] = b1[j];
#pragma unroll 1
    for (int kc = 0; kc < 8; ++kc) {
        float xr[16];
        if (kc < 4) {
            load16(hin, offH + kc * 16, isbf, xr);
        } else {
            load16f(pm + (kc - 4) * 16, xr);
#pragma unroll
            for (int k = 0; k < 16; ++k) xr[k] *= scale;
        }
#pragma unroll
        for (int k = 0; k < 16; ++k)
#pragma unroll
            for (int j = 0; j < 64; ++j)
                h[j] = fmaf(xr[k], w1[(kc * 16 + k) * 64 + j], h[j]);
    }
#pragma unroll
    for (int j = 0; j < 64; ++j) h[j] = fmaxf(h[j], 0.0f);

    float acc[64];
#pragma unroll
    for (int o = 0; o < 64; ++o) acc[o] = b2[o];
#pragma unroll
    for (int j = 0; j < 64; ++j)
#pragma unroll
        for (int o = 0; o < 64; ++o)
            acc[o] = fmaf(h[j], w2[j * 64 + o], acc[o]);

    if (isbf) {
        unsigned int ob[32];
#pragma unroll
        for (int i = 0; i < 32; ++i) {
            __hip_bfloat162 p2 = __float22bfloat162_rn(make_float2(acc[2 * i], acc[2 * i + 1]));
            ob[i] = *reinterpret_cast<unsigned int*>(&p2);
        }
        uint4* qo = reinterpret_cast<uint4*>((__hip_bfloat16*)out_b + offH);
#pragma unroll
        for (int i = 0; i < 8; ++i) qo[i] = make_uint4(ob[4*i], ob[4*i+1], ob[4*i+2], ob[4*i+3]);
    } else {
        float4* qf = reinterpret_cast<float4*>((float*)out_f + offH);
#pragma unroll
        for (int i = 0; i < 16; ++i) qf[i] = make_float4(acc[4*i], acc[4*i+1], acc[4*i+2], acc[4*i+3]);
    }
}

extern "C" void kernel_launch(void* const* d_in, const int* in_sizes, int n_in,
                              void* d_out, int out_size, void* d_ws, size_t ws_size,
                              hipStream_t stream) {
    const void* h_v    = d_in[0];
    const void* h_u    = d_in[1];
    const void* e_feat = d_in[2];
    const int* eidx = (const int*)d_in[3];
    const int* Sptr = (const int*)d_in[4];

    const int NV_ = in_sizes[0] / 64;
    const int NU_ = in_sizes[1] / 64;
    const int E_  = in_sizes[2] / 64;
    const int* src = eidx;        // edge_index row 0 (indexes h_v)
    const int* dst = eidx + E_;   // edge_index row 1 (indexes h_u)

    const int maxN = (NV_ > NU_) ? NV_ : NU_;
    // ws layout: flag (64B) | mbuf[maxN*64] f32 | degv[NV] f32 | wf (f32 weights) | packed bf16 frags
    int*   flag = (int*)d_ws;
    float* mbuf = (float*)((char*)d_ws + 64);
    float* degv = mbuf + (size_t)maxN * 64;
    float* wf   = degv + NV_;

    WArgs wa;
    int accum = 0;
    int maxCnt = 0;
    for (int i = 0; i < 16; ++i) {
        wa.p[i] = d_in[5 + i];
        wa.off[i] = accum;
        wa.cnt[i] = in_sizes[5 + i];
        accum += in_sizes[5 + i];
        if (in_sizes[5 + i] > maxCnt) maxCnt = in_sizes[5 + i];
    }

    // Packed fragment buffers (hi/lo bf16) after wf.
    const int W1P = 8 * 6 * 64 * 8;   // 24576
    const int W2P = 4 * 4 * 64 * 8;   // 8192
    ushort* pk = (ushort*)(wf + accum);
    ushort* p1w1hi = pk;
    ushort* p1w1lo = p1w1hi + W1P;
    ushort* p1w2hi = p1w1lo + W1P;
    ushort* p1w2lo = p1w2hi + W2P;
    ushort* p3w1hi = p1w2lo + W2P;
    ushort* p3w1lo = p3w1hi + W1P;
    ushort* p3w2hi = p3w1lo + W1P;
    ushort* p3w2lo = p3w2hi + W2P;

    detect_kernel<<<1, 512, 0, stream>>>((const unsigned int*)h_v, flag);

    dim3 cg((maxCnt + 255) / 256, 16);
    cvt_all<<<cg, 256, 0, stream>>>(wa, wf, flag);

    pack_w1<<<(W1P + 255) / 256, 256, 0, stream>>>(wf + wa.off[0], p1w1hi, p1w1lo);
    pack_w2<<<(W2P + 255) / 256, 256, 0, stream>>>(wf + wa.off[2], p1w2hi, p1w2lo);
    pack_w1<<<(W1P + 255) / 256, 256, 0, stream>>>(wf + wa.off[8], p3w1hi, p3w1lo);
    pack_w2<<<(W2P + 255) / 256, 256, 0, stream>>>(wf + wa.off[10], p3w2hi, p3w2lo);

    // Output regions per dtype interpretation.
    void* out_hv_f = d_out;
    void* out_hu_f = (void*)((float*)d_out + (size_t)NV_ * 64);
    void* out_hu_b = (void*)((__hip_bfloat16*)d_out + (size_t)NV_ * 64);

    hipMemsetAsync(mbuf, 0, (size_t)maxN * 64 * sizeof(float), stream);

    const int egrid   = (E_ + 63) / 64;
    const int egrid32 = (E_ + 31) / 32;

    // phase 1: A=h_v rows(src), B=h_u rows(dst), scatter by dst
    edge_mlp<<<egrid, 64, 0, stream>>>(h_v, h_v, h_u, e_feat, src, dst, flag,
        wf + wa.off[0], wf + wa.off[1], wf + wa.off[2], wf + wa.off[3], mbuf, E_, 0);
    edge_mlp_mfma<<<egrid32, 64, 0, stream>>>(h_v, h_u, e_feat, src, dst, flag,
        p1w1hi, p1w1lo, p1w2hi, p1w2lo,
        wf + wa.off[1], wf + wa.off[3], mbuf, E_, 0);

    const int ngridU = (NU_ + 255) / 256;
    node_mlp<<<ngridU, 256, 0, stream>>>(h_u, mbuf, nullptr, Sptr, flag,
        wf + wa.off[4], wf + wa.off[5], wf + wa.off[6], wf + wa.off[7],
        out_hu_f, out_hu_b, NU_, 0);

    hipMemsetAsync(mbuf, 0, (size_t)maxN * 64 * sizeof(float), stream);
    hipMemsetAsync(degv, 0, (size_t)NV_ * sizeof(float), stream);

    deg_kernel<<<(E_ + 255) / 256, 256, 0, stream>>>(src, degv, E_);

    // phase 3: A=h_u_out rows(dst), B=h_v rows(src), scatter by src
    edge_mlp<<<egrid, 64, 0, stream>>>(out_hu_f, out_hu_b, h_v, e_feat, src, dst, flag,
        wf + wa.off[8], wf + wa.off[9], wf + wa.off[10], wf + wa.off[11], mbuf, E_, 1);
    edge_mlp_mfma<<<egrid32, 64, 0, stream>>>(out_hu_b, h_v, e_feat, src, dst, flag,
        p3w1hi, p3w1lo, p3w2hi, p3w2lo,
        wf + wa.off[9], wf + wa.off[11], mbuf, E_, 1);

    const int ngridV = (NV_ + 255) / 256;
    node_mlp<<<ngridV, 256, 0, stream>>>(h_v, mbuf, degv, Sptr, flag,
        wf + wa.off[12], wf + wa.off[13], wf + wa.off[14], wf + wa.off[15],
        out_hv_f, d_out, NV_, 1);
}

// Round 4
// 1002.089 us; speedup vs baseline: 2.2963x; 2.2963x over previous
//
#include <hip/hip_runtime.h>
#include <hip/hip_bf16.h>
#include <stdint.h>

// SparseMPNNLayer: bipartite MPNN, H=64. Round 5: MFMA edge MLP for **f32 inputs**.
//  R3 post-mortem: detect flag==0 (inputs are f32; in_npz size + FETCH_SIZE confirm) —
//  the R2/R3 MFMA path was bf16-only and never executed. This round the MFMA kernel
//  handles f32 by on-the-fly split x = xhi + xlo (bf16 RNE each):
//   layer1: 3 MFMA passes (xhi*whi + xhi*wlo + xlo*whi) ~ 2^-18 input precision.
//   layer2: OUT^T = W2^T x H^T, H split hi/lo through LDS, 3 passes (as before).
//  Weights pre-split hi/lo bf16 on device (pack_w1/pack_w2). VALU edge fallback DELETED.
//  Epilogue: LDS transpose -> coalesced wave-wide row atomicAdd (32M atomics, unchanged).
//  Issue per 32-edge wave: ~384 MFMA + ~400 VALU convert vs 32768 VALU FMA before.

typedef __attribute__((ext_vector_type(8))) short short8v;   // 8 bf16 (4 VGPRs)
typedef __attribute__((ext_vector_type(4))) float f32x4;

__device__ __forceinline__ ushort f2bf_rn(float f) {
    union { float f; unsigned int u; } v; v.f = f;
    unsigned int u = v.u;
    unsigned int r = u + 0x7fffu + ((u >> 16) & 1u);   // round-to-nearest-even
    return (ushort)(r >> 16);
}
__device__ __forceinline__ float bf2f(ushort h) {
    union { unsigned int u; float f; } v; v.u = ((unsigned int)h) << 16;
    return v.f;
}

__device__ __forceinline__ void unpack2(unsigned int u, float& a, float& b) {
    union { unsigned int i; float f; } x, y;
    x.i = u << 16;
    y.i = u & 0xffff0000u;
    a = x.f; b = y.f;
}

__device__ __forceinline__ void load16bf(const __hip_bfloat16* __restrict__ p, float* xr) {
    const uint4* q = reinterpret_cast<const uint4*>(p);
    uint4 a = q[0];
    uint4 b = q[1];
    unpack2(a.x, xr[0], xr[1]);  unpack2(a.y, xr[2], xr[3]);
    unpack2(a.z, xr[4], xr[5]);  unpack2(a.w, xr[6], xr[7]);
    unpack2(b.x, xr[8], xr[9]);  unpack2(b.y, xr[10], xr[11]);
    unpack2(b.z, xr[12], xr[13]); unpack2(b.w, xr[14], xr[15]);
}

__device__ __forceinline__ void load16f(const float* __restrict__ p, float* xr) {
    const float4* q = reinterpret_cast<const float4*>(p);
#pragma unroll
    for (int i = 0; i < 4; ++i) {
        float4 v = q[i];
        xr[4*i+0] = v.x; xr[4*i+1] = v.y; xr[4*i+2] = v.z; xr[4*i+3] = v.w;
    }
}

__device__ __forceinline__ void load16(const void* base, size_t off, int isbf, float* xr) {
    if (isbf) load16bf((const __hip_bfloat16*)base + off, xr);
    else      load16f((const float*)base + off, xr);
}

__device__ __forceinline__ void ld8f(const float* __restrict__ p, float* t) {
    float4 a = *(const float4*)p;
    float4 b = *(const float4*)(p + 4);
    t[0]=a.x; t[1]=a.y; t[2]=a.z; t[3]=a.w;
    t[4]=b.x; t[5]=b.y; t[6]=b.z; t[7]=b.w;
}

// Split 8 f32 into hi/lo bf16 fragments (RNE both planes).
__device__ __forceinline__ void cvt8(const float* __restrict__ t, short8v& hi, short8v& lo) {
#pragma unroll
    for (int j = 0; j < 8; ++j) {
        ushort h = f2bf_rn(t[j]);
        hi[j] = (short)h;
        lo[j] = (short)f2bf_rn(t[j] - bf2f(h));
    }
}

// Classify storage of h_v: packed-bf16 pairs have a bf16 exponent field in the
// low 16 bits of each u32 (~99.7% in [100,140] for N(0,1)); f32 mantissa bits
// hit that window ~16% of the time.
__global__ void detect_kernel(const unsigned int* __restrict__ hv, int* __restrict__ flag) {
    __shared__ int cnt;
    if (threadIdx.x == 0) cnt = 0;
    __syncthreads();
    unsigned int w = hv[threadIdx.x];
    int ef = (w >> 7) & 0xff;
    if (ef >= 100 && ef <= 140) atomicAdd(&cnt, 1);
    __syncthreads();
    if (threadIdx.x == 0) flag[0] = (cnt > 256) ? 1 : 0;
}

struct WArgs {
    const void* p[16];
    int off[16];
    int cnt[16];
};

__global__ void cvt_all(WArgs wa, float* __restrict__ wf, const int* __restrict__ gflag) {
    const int isbf = gflag[0];
    const int t = blockIdx.y;
    const int i = blockIdx.x * 256 + threadIdx.x;
    if (i >= wa.cnt[t]) return;
    wf[wa.off[t] + i] = isbf ? __bfloat162float(((const __hip_bfloat16*)wa.p[t])[i])
                             : ((const float*)wa.p[t])[i];
}

// Pack W1 (f32 192x128) into MFMA B-fragment order for 16x16x32, split hi/lo bf16.
// Layout: [nt(8)][kt(6)][lane(64)][j(8)]; element = w1[(kt*32 + (lane>>4)*8 + j)*128 + nt*16 + (lane&15)]
__global__ void pack_w1(const float* __restrict__ w1, ushort* __restrict__ hi, ushort* __restrict__ lo) {
    int i = blockIdx.x * 256 + threadIdx.x;
    if (i >= 8 * 6 * 64 * 8) return;
    int j = i & 7;
    int lane = (i >> 3) & 63;
    int t = i >> 9;
    int kt = t % 6, nt = t / 6;
    float w = w1[(kt * 32 + (lane >> 4) * 8 + j) * 128 + nt * 16 + (lane & 15)];
    ushort h = f2bf_rn(w);
    hi[i] = h;
    lo[i] = f2bf_rn(w - bf2f(h));
}

// Pack W2^T (from w2 f32 128x64) into MFMA A-fragment order for 16x16x32, split hi/lo.
// Layout: [pair(4)][ot(4)][lane(64)][j(8)]; element = w2[(pair*32 + (lane>>4)*8 + j)*64 + ot*16 + (lane&15)]
__global__ void pack_w2(const float* __restrict__ w2, ushort* __restrict__ hi, ushort* __restrict__ lo) {
    int i = blockIdx.x * 256 + threadIdx.x;
    if (i >= 4 * 4 * 64 * 8) return;
    int j = i & 7;
    int lane = (i >> 3) & 63;
    int t = i >> 9;
    int ot = t & 3, pair = t >> 2;
    float w = w2[(pair * 32 + (lane >> 4) * 8 + j) * 64 + ot * 16 + (lane & 15)];
    ushort h = f2bf_rn(w);
    hi[i] = h;
    lo[i] = f2bf_rn(w - bf2f(h));
}

__global__ void deg_kernel(const int* __restrict__ src, float* __restrict__ degv, int E) {
    int e = blockIdx.x * 256 + threadIdx.x;
    if (e < E) atomicAdd(&degv[src[e]], 1.0f);
}

// ---------------- MFMA edge MLP (dtype by template; dead launch for the other) ----
// One wave per block, 32 edges. x = [A-rows | B-rows | e_feat] (each 64 elems).
// ph3==0: A=h_v rows idx src, B=h_u rows idx dst, scatter row = dst
// ph3==1: A=h_u_out rows idx dst, B=h_v rows idx src, scatter row = src
template <int ISBF>
__global__ __launch_bounds__(64)
void edge_mlp_mfma(const void* __restrict__ A_, const void* __restrict__ B_,
                   const void* __restrict__ E_,
                   const int* __restrict__ src_idx, const int* __restrict__ dst_idx,
                   const int* __restrict__ gflag,
                   const ushort* __restrict__ w1hi, const ushort* __restrict__ w1lo,
                   const ushort* __restrict__ w2hi, const ushort* __restrict__ w2lo,
                   const float* __restrict__ b1, const float* __restrict__ b2,
                   float* __restrict__ accum, int E, int ph3) {
    if (gflag[0] != ISBF) return;

    __shared__ ushort hb_hi[32][40];   // H tile hi, row stride 80B (16B-aligned reads)
    __shared__ ushort hb_lo[32][40];   // H tile lo
    __shared__ float  smt[32][17];     // epilogue transpose
    __shared__ int rowS[32], gA[32], gB[32];

    const int lane = threadIdx.x;
    const int base = blockIdx.x * 32;
    const int cnt = min(32, E - base);
    const int eloc = lane & 15;            // N-dim / col lane index
    const int khalf = (lane >> 4) * 8;     // K-slice base within a K=32 tile

    if (lane < 32) {
        int e = base + ((lane < cnt) ? lane : (cnt - 1));
        int s = src_idx[e], d = dst_idx[e];
        rowS[lane] = ph3 ? s : d;
        gA[lane]   = ph3 ? d : s;
        gB[lane]   = ph3 ? s : d;
    }
    __syncthreads();

    // Gather + split all A-fragments up front: ah/al[kt][mt], 16B/lane fragments.
    short8v ah[6][2];
    short8v al[6][2];
#pragma unroll
    for (int mt = 0; mt < 2; ++mt) {
        const int el = mt * 16 + eloc;
        const int elc = (el < cnt) ? el : (cnt - 1);
        if (ISBF) {
            const ushort* ra = (const ushort*)A_ + (size_t)gA[elc] * 64;
            const ushort* rb = (const ushort*)B_ + (size_t)gB[elc] * 64;
            const ushort* re = (const ushort*)E_ + (size_t)(base + elc) * 64;
            ah[0][mt] = *(const short8v*)(ra + khalf);
            ah[1][mt] = *(const short8v*)(ra + 32 + khalf);
            ah[2][mt] = *(const short8v*)(rb + khalf);
            ah[3][mt] = *(const short8v*)(rb + 32 + khalf);
            ah[4][mt] = *(const short8v*)(re + khalf);
            ah[5][mt] = *(const short8v*)(re + 32 + khalf);
        } else {
            const float* ra = (const float*)A_ + (size_t)gA[elc] * 64;
            const float* rb = (const float*)B_ + (size_t)gB[elc] * 64;
            const float* re = (const float*)E_ + (size_t)(base + elc) * 64;
            float t[8];
            ld8f(ra + khalf, t);      cvt8(t, ah[0][mt], al[0][mt]);
            ld8f(ra + 32 + khalf, t); cvt8(t, ah[1][mt], al[1][mt]);
            ld8f(rb + khalf, t);      cvt8(t, ah[2][mt], al[2][mt]);
            ld8f(rb + 32 + khalf, t); cvt8(t, ah[3][mt], al[3][mt]);
            ld8f(re + khalf, t);      cvt8(t, ah[4][mt], al[4][mt]);
            ld8f(re + 32 + khalf, t); cvt8(t, ah[5][mt], al[5][mt]);
        }
    }

    // acc2 = OUT^T tiles [ot(out 64/16)][et(edge 32/16)], init with b2[out] (per-message bias).
    f32x4 acc2[4][2];
#pragma unroll
    for (int ot = 0; ot < 4; ++ot)
#pragma unroll
        for (int r = 0; r < 4; ++r) {
            float bv = b2[ot * 16 + (lane >> 4) * 4 + r];
            acc2[ot][0][r] = bv;
            acc2[ot][1][r] = bv;
        }

#pragma unroll 1
    for (int pair = 0; pair < 4; ++pair) {           // 32 hidden per pair
#pragma unroll
        for (int nt2 = 0; nt2 < 2; ++nt2) {          // 16 hidden per ntile
            const int nt = pair * 2 + nt2;
            const float bv = b1[nt * 16 + eloc];
            f32x4 c1[2];
#pragma unroll
            for (int mt = 0; mt < 2; ++mt) {
                c1[mt][0] = bv; c1[mt][1] = bv; c1[mt][2] = bv; c1[mt][3] = bv;
            }
#pragma unroll
            for (int kt = 0; kt < 6; ++kt) {
                const size_t wo = (((size_t)(nt * 6 + kt)) * 64 + lane) * 8;
                const short8v bh = *(const short8v*)(w1hi + wo);
                const short8v bl = *(const short8v*)(w1lo + wo);
#pragma unroll
                for (int mt = 0; mt < 2; ++mt) {
                    c1[mt] = __builtin_amdgcn_mfma_f32_16x16x32_bf16(ah[kt][mt], bh, c1[mt], 0, 0, 0);
                    c1[mt] = __builtin_amdgcn_mfma_f32_16x16x32_bf16(ah[kt][mt], bl, c1[mt], 0, 0, 0);
                    if (!ISBF)
                        c1[mt] = __builtin_amdgcn_mfma_f32_16x16x32_bf16(al[kt][mt], bh, c1[mt], 0, 0, 0);
                }
            }
            // relu + split f32 -> hi/lo bf16, store H^T staging (C layout: col=lane&15=hidden,
            // row=(lane>>4)*4+r=edge)
#pragma unroll
            for (int mt = 0; mt < 2; ++mt)
#pragma unroll
                for (int r = 0; r < 4; ++r) {
                    float v = fmaxf(c1[mt][r], 0.0f);
                    ushort h = f2bf_rn(v);
                    ushort l = f2bf_rn(v - bf2f(h));
                    const int er = mt * 16 + (lane >> 4) * 4 + r;
                    hb_hi[er][nt2 * 16 + eloc] = h;
                    hb_lo[er][nt2 * 16 + eloc] = l;
                }
        }
        __syncthreads();
        // layer2: OUT^T += W2^T[:, pair-hid32] x H^T[pair-hid32, :]
#pragma unroll
        for (int et = 0; et < 2; ++et) {
            const short8v bh = *(const short8v*)(&hb_hi[et * 16 + eloc][khalf]);
            const short8v bl = *(const short8v*)(&hb_lo[et * 16 + eloc][khalf]);
#pragma unroll
            for (int ot = 0; ot < 4; ++ot) {
                const size_t wo = (((size_t)(pair * 4 + ot)) * 64 + lane) * 8;
                const short8v wh = *(const short8v*)(w2hi + wo);
                const short8v wl = *(const short8v*)(w2lo + wo);
                acc2[ot][et] = __builtin_amdgcn_mfma_f32_16x16x32_bf16(wh, bh, acc2[ot][et], 0, 0, 0);
                acc2[ot][et] = __builtin_amdgcn_mfma_f32_16x16x32_bf16(wh, bl, acc2[ot][et], 0, 0, 0);
                acc2[ot][et] = __builtin_amdgcn_mfma_f32_16x16x32_bf16(wl, bh, acc2[ot][et], 0, 0, 0);
            }
        }
        __syncthreads();
    }

    // Epilogue: transpose OUT^T tiles through LDS -> coalesced row-wise atomics.
#pragma unroll 1
    for (int ot = 0; ot < 4; ++ot) {
        __syncthreads();
#pragma unroll
        for (int et = 0; et < 2; ++et)
#pragma unroll
            for (int r = 0; r < 4; ++r)
                smt[et * 16 + eloc][(lane >> 4) * 4 + r] = acc2[ot][et][r];
        __syncthreads();
#pragma unroll 1
        for (int i = 0; i < 32; i += 4) {
            const int e = i + (lane >> 4);
            if (e < cnt)
                atomicAdd(&accum[(size_t)rowS[e] * 64 + ot * 16 + eloc], smt[e][eloc]);
        }
    }
}

// Node MLP: K=128 -> 64 (relu) -> 64. Full h[64] in regs -> x loaded once.
__global__ __launch_bounds__(256)
void node_mlp(const void* __restrict__ hin,
              const float* __restrict__ m,
              const float* __restrict__ degv,
              const int* __restrict__ Sptr,
              const int* __restrict__ gflag,
              const float* __restrict__ w1, const float* __restrict__ b1,
              const float* __restrict__ w2, const float* __restrict__ b2,
              void* __restrict__ out_f, void* __restrict__ out_b,
              int N, int ph4) {
    const int isbf = gflag[0];
    const int n = blockIdx.x * 256 + threadIdx.x;
    if (n >= N) return;
    const float scale = ph4 ? (1.0f / fmaxf(degv[n], 1.0f))
                            : (1.0f / (float)Sptr[0]);
    const size_t offH = (size_t)n * 64;
    const float* pm = m + offH;

    float h[64];
#pragma unroll
    for (int j = 0; j < 64; ++j) h[j] = b1[j];
#pragma unroll 1
    for (int kc = 0; kc < 8; ++kc) {
        float xr[16];
        if (kc < 4) {
            load16(hin, offH + kc * 16, isbf, xr);
        } else {
            load16f(pm + (kc - 4) * 16, xr);
#pragma unroll
            for (int k = 0; k < 16; ++k) xr[k] *= scale;
        }
#pragma unroll
        for (int k = 0; k < 16; ++k)
#pragma unroll
            for (int j = 0; j < 64; ++j)
                h[j] = fmaf(xr[k], w1[(kc * 16 + k) * 64 + j], h[j]);
    }
#pragma unroll
    for (int j = 0; j < 64; ++j) h[j] = fmaxf(h[j], 0.0f);

    float acc[64];
#pragma unroll
    for (int o = 0; o < 64; ++o) acc[o] = b2[o];
#pragma unroll
    for (int j = 0; j < 64; ++j)
#pragma unroll
        for (int o = 0; o < 64; ++o)
            acc[o] = fmaf(h[j], w2[j * 64 + o], acc[o]);

    if (isbf) {
        unsigned int ob[32];
#pragma unroll
        for (int i = 0; i < 32; ++i) {
            __hip_bfloat162 p2 = __float22bfloat162_rn(make_float2(acc[2 * i], acc[2 * i + 1]));
            ob[i] = *reinterpret_cast<unsigned int*>(&p2);
        }
        uint4* qo = reinterpret_cast<uint4*>((__hip_bfloat16*)out_b + offH);
#pragma unroll
        for (int i = 0; i < 8; ++i) qo[i] = make_uint4(ob[4*i], ob[4*i+1], ob[4*i+2], ob[4*i+3]);
    } else {
        float4* qf = reinterpret_cast<float4*>((float*)out_f + offH);
#pragma unroll
        for (int i = 0; i < 16; ++i) qf[i] = make_float4(acc[4*i], acc[4*i+1], acc[4*i+2], acc[4*i+3]);
    }
}

extern "C" void kernel_launch(void* const* d_in, const int* in_sizes, int n_in,
                              void* d_out, int out_size, void* d_ws, size_t ws_size,
                              hipStream_t stream) {
    const void* h_v    = d_in[0];
    const void* h_u    = d_in[1];
    const void* e_feat = d_in[2];
    const int* eidx = (const int*)d_in[3];
    const int* Sptr = (const int*)d_in[4];

    const int NV_ = in_sizes[0] / 64;
    const int NU_ = in_sizes[1] / 64;
    const int E_  = in_sizes[2] / 64;
    const int* src = eidx;        // edge_index row 0 (indexes h_v)
    const int* dst = eidx + E_;   // edge_index row 1 (indexes h_u)

    const int maxN = (NV_ > NU_) ? NV_ : NU_;
    // ws layout: flag (64B) | mbuf[maxN*64] f32 | degv[NV] f32 | wf (f32 weights) | packed bf16 frags
    int*   flag = (int*)d_ws;
    float* mbuf = (float*)((char*)d_ws + 64);
    float* degv = mbuf + (size_t)maxN * 64;
    float* wf   = degv + NV_;

    WArgs wa;
    int accum = 0;
    int maxCnt = 0;
    for (int i = 0; i < 16; ++i) {
        wa.p[i] = d_in[5 + i];
        wa.off[i] = accum;
        wa.cnt[i] = in_sizes[5 + i];
        accum += in_sizes[5 + i];
        if (in_sizes[5 + i] > maxCnt) maxCnt = in_sizes[5 + i];
    }

    // Packed fragment buffers (hi/lo bf16) after wf.
    const int W1P = 8 * 6 * 64 * 8;   // 24576
    const int W2P = 4 * 4 * 64 * 8;   // 8192
    ushort* pk = (ushort*)(wf + accum);
    ushort* p1w1hi = pk;
    ushort* p1w1lo = p1w1hi + W1P;
    ushort* p1w2hi = p1w1lo + W1P;
    ushort* p1w2lo = p1w2hi + W2P;
    ushort* p3w1hi = p1w2lo + W2P;
    ushort* p3w1lo = p3w1hi + W1P;
    ushort* p3w2hi = p3w1lo + W1P;
    ushort* p3w2lo = p3w2hi + W2P;

    detect_kernel<<<1, 512, 0, stream>>>((const unsigned int*)h_v, flag);

    dim3 cg((maxCnt + 255) / 256, 16);
    cvt_all<<<cg, 256, 0, stream>>>(wa, wf, flag);

    pack_w1<<<(W1P + 255) / 256, 256, 0, stream>>>(wf + wa.off[0], p1w1hi, p1w1lo);
    pack_w2<<<(W2P + 255) / 256, 256, 0, stream>>>(wf + wa.off[2], p1w2hi, p1w2lo);
    pack_w1<<<(W1P + 255) / 256, 256, 0, stream>>>(wf + wa.off[8], p3w1hi, p3w1lo);
    pack_w2<<<(W2P + 255) / 256, 256, 0, stream>>>(wf + wa.off[10], p3w2hi, p3w2lo);

    // Output regions per dtype interpretation.
    void* out_hv_f = d_out;
    void* out_hu_f = (void*)((float*)d_out + (size_t)NV_ * 64);
    void* out_hu_b = (void*)((__hip_bfloat16*)d_out + (size_t)NV_ * 64);

    hipMemsetAsync(mbuf, 0, (size_t)maxN * 64 * sizeof(float), stream);

    const int egrid32 = (E_ + 31) / 32;

    // phase 1: A=h_v rows(src), B=h_u rows(dst), scatter by dst
    edge_mlp_mfma<0><<<egrid32, 64, 0, stream>>>(h_v, h_u, e_feat, src, dst, flag,
        p1w1hi, p1w1lo, p1w2hi, p1w2lo,
        wf + wa.off[1], wf + wa.off[3], mbuf, E_, 0);
    edge_mlp_mfma<1><<<egrid32, 64, 0, stream>>>(h_v, h_u, e_feat, src, dst, flag,
        p1w1hi, p1w1lo, p1w2hi, p1w2lo,
        wf + wa.off[1], wf + wa.off[3], mbuf, E_, 0);

    const int ngridU = (NU_ + 255) / 256;
    node_mlp<<<ngridU, 256, 0, stream>>>(h_u, mbuf, nullptr, Sptr, flag,
        wf + wa.off[4], wf + wa.off[5], wf + wa.off[6], wf + wa.off[7],
        out_hu_f, out_hu_b, NU_, 0);

    hipMemsetAsync(mbuf, 0, (size_t)maxN * 64 * sizeof(float), stream);
    hipMemsetAsync(degv, 0, (size_t)NV_ * sizeof(float), stream);

    deg_kernel<<<(E_ + 255) / 256, 256, 0, stream>>>(src, degv, E_);

    // phase 3: A=h_u_out rows(dst), B=h_v rows(src), scatter by src
    edge_mlp_mfma<0><<<egrid32, 64, 0, stream>>>(out_hu_f, h_v, e_feat, src, dst, flag,
        p3w1hi, p3w1lo, p3w2hi, p3w2lo,
        wf + wa.off[9], wf + wa.off[11], mbuf, E_, 1);
    edge_mlp_mfma<1><<<egrid32, 64, 0, stream>>>(out_hu_b, h_v, e_feat, src, dst, flag,
        p3w1hi, p3w1lo, p3w2hi, p3w2lo,
        wf + wa.off[9], wf + wa.off[11], mbuf, E_, 1);

    const int ngridV = (NV_ + 255) / 256;
    node_mlp<<<ngridV, 256, 0, stream>>>(h_v, mbuf, degv, Sptr, flag,
        wf + wa.off[12], wf + wa.off[13], wf + wa.off[14], wf + wa.off[15],
        out_hv_f, d_out, NV_, 1);
}

// Round 5
// 938.378 us; speedup vs baseline: 2.4522x; 1.0679x over previous
//
#include <hip/hip_runtime.h>
#include <hip/hip_bf16.h>
#include <stdint.h>

// SparseMPNNLayer: bipartite MPNN, H=64. Round 6: 16-edge waves for register relief.
//  R4 post-mortem: 32-edge wave carried ~170 live regs (X hi/lo frags 96 + acc 32+)
//  -> 2 waves/SIMD AND no scheduler headroom to hoist gathers/weight loads -> loads
//  pay ~full latency serially (~90K cyc/wave vs ~12K static). This round: 16 edges
//  per wave (X frags 48, acc2 16, ~100 total) + __launch_bounds__(64,4) -> 4
//  waves/SIMD band + load hoisting restored. MFMA/edge unchanged (M=16 tile full).
//  Same math: layer1 3-pass split (xhi*whi + xhi*wlo + xlo*whi), layer2 3-pass via
//  LDS-staged split H. Epilogue: LDS transpose -> wave-wide row atomicAdd.

typedef __attribute__((ext_vector_type(8))) short short8v;   // 8 bf16 (4 VGPRs)
typedef __attribute__((ext_vector_type(4))) float f32x4;

__device__ __forceinline__ ushort f2bf_rn(float f) {
    union { float f; unsigned int u; } v; v.f = f;
    unsigned int u = v.u;
    unsigned int r = u + 0x7fffu + ((u >> 16) & 1u);   // round-to-nearest-even
    return (ushort)(r >> 16);
}
__device__ __forceinline__ float bf2f(ushort h) {
    union { unsigned int u; float f; } v; v.u = ((unsigned int)h) << 16;
    return v.f;
}

__device__ __forceinline__ void unpack2(unsigned int u, float& a, float& b) {
    union { unsigned int i; float f; } x, y;
    x.i = u << 16;
    y.i = u & 0xffff0000u;
    a = x.f; b = y.f;
}

__device__ __forceinline__ void load16bf(const __hip_bfloat16* __restrict__ p, float* xr) {
    const uint4* q = reinterpret_cast<const uint4*>(p);
    uint4 a = q[0];
    uint4 b = q[1];
    unpack2(a.x, xr[0], xr[1]);  unpack2(a.y, xr[2], xr[3]);
    unpack2(a.z, xr[4], xr[5]);  unpack2(a.w, xr[6], xr[7]);
    unpack2(b.x, xr[8], xr[9]);  unpack2(b.y, xr[10], xr[11]);
    unpack2(b.z, xr[12], xr[13]); unpack2(b.w, xr[14], xr[15]);
}

__device__ __forceinline__ void load16f(const float* __restrict__ p, float* xr) {
    const float4* q = reinterpret_cast<const float4*>(p);
#pragma unroll
    for (int i = 0; i < 4; ++i) {
        float4 v = q[i];
        xr[4*i+0] = v.x; xr[4*i+1] = v.y; xr[4*i+2] = v.z; xr[4*i+3] = v.w;
    }
}

__device__ __forceinline__ void load16(const void* base, size_t off, int isbf, float* xr) {
    if (isbf) load16bf((const __hip_bfloat16*)base + off, xr);
    else      load16f((const float*)base + off, xr);
}

__device__ __forceinline__ void ld8f(const float* __restrict__ p, float* t) {
    float4 a = *(const float4*)p;
    float4 b = *(const float4*)(p + 4);
    t[0]=a.x; t[1]=a.y; t[2]=a.z; t[3]=a.w;
    t[4]=b.x; t[5]=b.y; t[6]=b.z; t[7]=b.w;
}

// Split 8 f32 into hi/lo bf16 fragments (RNE both planes).
__device__ __forceinline__ void cvt8(const float* __restrict__ t, short8v& hi, short8v& lo) {
#pragma unroll
    for (int j = 0; j < 8; ++j) {
        ushort h = f2bf_rn(t[j]);
        hi[j] = (short)h;
        lo[j] = (short)f2bf_rn(t[j] - bf2f(h));
    }
}

// Classify storage of h_v: packed-bf16 pairs have a bf16 exponent field in the
// low 16 bits of each u32 (~99.7% in [100,140] for N(0,1)); f32 mantissa bits
// hit that window ~16% of the time.
__global__ void detect_kernel(const unsigned int* __restrict__ hv, int* __restrict__ flag) {
    __shared__ int cnt;
    if (threadIdx.x == 0) cnt = 0;
    __syncthreads();
    unsigned int w = hv[threadIdx.x];
    int ef = (w >> 7) & 0xff;
    if (ef >= 100 && ef <= 140) atomicAdd(&cnt, 1);
    __syncthreads();
    if (threadIdx.x == 0) flag[0] = (cnt > 256) ? 1 : 0;
}

struct WArgs {
    const void* p[16];
    int off[16];
    int cnt[16];
};

__global__ void cvt_all(WArgs wa, float* __restrict__ wf, const int* __restrict__ gflag) {
    const int isbf = gflag[0];
    const int t = blockIdx.y;
    const int i = blockIdx.x * 256 + threadIdx.x;
    if (i >= wa.cnt[t]) return;
    wf[wa.off[t] + i] = isbf ? __bfloat162float(((const __hip_bfloat16*)wa.p[t])[i])
                             : ((const float*)wa.p[t])[i];
}

// Pack W1 (f32 192x128) into MFMA B-fragment order for 16x16x32, split hi/lo bf16.
// Layout: [nt(8)][kt(6)][lane(64)][j(8)]; element = w1[(kt*32 + (lane>>4)*8 + j)*128 + nt*16 + (lane&15)]
__global__ void pack_w1(const float* __restrict__ w1, ushort* __restrict__ hi, ushort* __restrict__ lo) {
    int i = blockIdx.x * 256 + threadIdx.x;
    if (i >= 8 * 6 * 64 * 8) return;
    int j = i & 7;
    int lane = (i >> 3) & 63;
    int t = i >> 9;
    int kt = t % 6, nt = t / 6;
    float w = w1[(kt * 32 + (lane >> 4) * 8 + j) * 128 + nt * 16 + (lane & 15)];
    ushort h = f2bf_rn(w);
    hi[i] = h;
    lo[i] = f2bf_rn(w - bf2f(h));
}

// Pack W2^T (from w2 f32 128x64) into MFMA A-fragment order for 16x16x32, split hi/lo.
// Layout: [pair(4)][ot(4)][lane(64)][j(8)]; element = w2[(pair*32 + (lane>>4)*8 + j)*64 + ot*16 + (lane&15)]
__global__ void pack_w2(const float* __restrict__ w2, ushort* __restrict__ hi, ushort* __restrict__ lo) {
    int i = blockIdx.x * 256 + threadIdx.x;
    if (i >= 4 * 4 * 64 * 8) return;
    int j = i & 7;
    int lane = (i >> 3) & 63;
    int t = i >> 9;
    int ot = t & 3, pair = t >> 2;
    float w = w2[(pair * 32 + (lane >> 4) * 8 + j) * 64 + ot * 16 + (lane & 15)];
    ushort h = f2bf_rn(w);
    hi[i] = h;
    lo[i] = f2bf_rn(w - bf2f(h));
}

__global__ void deg_kernel(const int* __restrict__ src, float* __restrict__ degv, int E) {
    int e = blockIdx.x * 256 + threadIdx.x;
    if (e < E) atomicAdd(&degv[src[e]], 1.0f);
}

// ---------------- MFMA edge MLP, 16 edges per 1-wave block ----------------
// x = [A-row | B-row | e_feat-row] (each 64 elems).
// ph3==0: A=h_v rows idx src, B=h_u rows idx dst, scatter row = dst
// ph3==1: A=h_u_out rows idx dst, B=h_v rows idx src, scatter row = src
template <int ISBF>
__global__ __launch_bounds__(64, 4)
void edge_mlp_mfma(const void* __restrict__ A_, const void* __restrict__ B_,
                   const void* __restrict__ E_,
                   const int* __restrict__ src_idx, const int* __restrict__ dst_idx,
                   const int* __restrict__ gflag,
                   const ushort* __restrict__ w1hi, const ushort* __restrict__ w1lo,
                   const ushort* __restrict__ w2hi, const ushort* __restrict__ w2lo,
                   const float* __restrict__ b1, const float* __restrict__ b2,
                   float* __restrict__ accum, int E, int ph3) {
    if (gflag[0] != ISBF) return;

    __shared__ ushort hb_hi[16][40];   // H tile hi, row stride 80B (16B-aligned reads)
    __shared__ ushort hb_lo[16][40];   // H tile lo
    __shared__ float  smt[16][17];     // epilogue transpose
    __shared__ int rowS[16], gA[16], gB[16];

    const int lane = threadIdx.x;
    const int base = blockIdx.x * 16;
    const int cnt = min(16, E - base);
    const int eloc = lane & 15;            // edge-row / col lane index
    const int khalf = (lane >> 4) * 8;     // K-slice base within a K=32 tile

    if (lane < 16) {
        int e = base + ((lane < cnt) ? lane : (cnt - 1));
        int s = src_idx[e], d = dst_idx[e];
        rowS[lane] = ph3 ? s : d;
        gA[lane]   = ph3 ? d : s;
        gB[lane]   = ph3 ? s : d;
    }
    __syncthreads();

    // Gather + split all A-fragments up front: ah/al[kt] (16B/lane fragments).
    short8v ah[6];
    short8v al[6];
    {
        const int elc = (eloc < cnt) ? eloc : (cnt - 1);
        if (ISBF) {
            const ushort* ra = (const ushort*)A_ + (size_t)gA[elc] * 64;
            const ushort* rb = (const ushort*)B_ + (size_t)gB[elc] * 64;
            const ushort* re = (const ushort*)E_ + (size_t)(base + elc) * 64;
            ah[0] = *(const short8v*)(ra + khalf);
            ah[1] = *(const short8v*)(ra + 32 + khalf);
            ah[2] = *(const short8v*)(rb + khalf);
            ah[3] = *(const short8v*)(rb + 32 + khalf);
            ah[4] = *(const short8v*)(re + khalf);
            ah[5] = *(const short8v*)(re + 32 + khalf);
        } else {
            const float* ra = (const float*)A_ + (size_t)gA[elc] * 64;
            const float* rb = (const float*)B_ + (size_t)gB[elc] * 64;
            const float* re = (const float*)E_ + (size_t)(base + elc) * 64;
            float t[8];
            ld8f(ra + khalf, t);      cvt8(t, ah[0], al[0]);
            ld8f(ra + 32 + khalf, t); cvt8(t, ah[1], al[1]);
            ld8f(rb + khalf, t);      cvt8(t, ah[2], al[2]);
            ld8f(rb + 32 + khalf, t); cvt8(t, ah[3], al[3]);
            ld8f(re + khalf, t);      cvt8(t, ah[4], al[4]);
            ld8f(re + 32 + khalf, t); cvt8(t, ah[5], al[5]);
        }
    }

    // acc2 = OUT^T tiles [ot(out 64/16)], col=edge(lane&15), row=out=(lane>>4)*4+r.
    f32x4 acc2[4];
#pragma unroll
    for (int ot = 0; ot < 4; ++ot)
#pragma unroll
        for (int r = 0; r < 4; ++r)
            acc2[ot][r] = b2[ot * 16 + (lane >> 4) * 4 + r];

#pragma unroll 1
    for (int pair = 0; pair < 4; ++pair) {           // 32 hidden per pair
#pragma unroll
        for (int nt2 = 0; nt2 < 2; ++nt2) {          // 16 hidden per ntile
            const int nt = pair * 2 + nt2;
            const float bv = b1[nt * 16 + eloc];
            f32x4 c1;
            c1[0] = bv; c1[1] = bv; c1[2] = bv; c1[3] = bv;
#pragma unroll
            for (int kt = 0; kt < 6; ++kt) {
                const size_t wo = (((size_t)(nt * 6 + kt)) * 64 + lane) * 8;
                const short8v bh = *(const short8v*)(w1hi + wo);
                const short8v bl = *(const short8v*)(w1lo + wo);
                c1 = __builtin_amdgcn_mfma_f32_16x16x32_bf16(ah[kt], bh, c1, 0, 0, 0);
                c1 = __builtin_amdgcn_mfma_f32_16x16x32_bf16(ah[kt], bl, c1, 0, 0, 0);
                if (!ISBF)
                    c1 = __builtin_amdgcn_mfma_f32_16x16x32_bf16(al[kt], bh, c1, 0, 0, 0);
            }
            // relu + split f32 -> hi/lo bf16, store H staging (C layout: col=lane&15=hidden,
            // row=(lane>>4)*4+r=edge)
#pragma unroll
            for (int r = 0; r < 4; ++r) {
                float v = fmaxf(c1[r], 0.0f);
                ushort h = f2bf_rn(v);
                ushort l = f2bf_rn(v - bf2f(h));
                const int er = (lane >> 4) * 4 + r;
                hb_hi[er][nt2 * 16 + eloc] = h;
                hb_lo[er][nt2 * 16 + eloc] = l;
            }
        }
        __syncthreads();
        // layer2: OUT^T += W2^T[:, pair-hid32] x H^T[pair-hid32, :]
        {
            const short8v bh = *(const short8v*)(&hb_hi[eloc][khalf]);
            const short8v bl = *(const short8v*)(&hb_lo[eloc][khalf]);
#pragma unroll
            for (int ot = 0; ot < 4; ++ot) {
                const size_t wo = (((size_t)(pair * 4 + ot)) * 64 + lane) * 8;
                const short8v wh = *(const short8v*)(w2hi + wo);
                const short8v wl = *(const short8v*)(w2lo + wo);
                acc2[ot] = __builtin_amdgcn_mfma_f32_16x16x32_bf16(wh, bh, acc2[ot], 0, 0, 0);
                acc2[ot] = __builtin_amdgcn_mfma_f32_16x16x32_bf16(wh, bl, acc2[ot], 0, 0, 0);
                acc2[ot] = __builtin_amdgcn_mfma_f32_16x16x32_bf16(wl, bh, acc2[ot], 0, 0, 0);
            }
        }
        __syncthreads();
    }

    // Epilogue: transpose OUT^T tiles through LDS -> coalesced row-wise atomics.
#pragma unroll 1
    for (int ot = 0; ot < 4; ++ot) {
        __syncthreads();
#pragma unroll
        for (int r = 0; r < 4; ++r)
            smt[eloc][(lane >> 4) * 4 + r] = acc2[ot][r];
        __syncthreads();
#pragma unroll 1
        for (int i = 0; i < 16; i += 4) {
            const int e = i + (lane >> 4);
            if (e < cnt)
                atomicAdd(&accum[(size_t)rowS[e] * 64 + ot * 16 + eloc], smt[e][eloc]);
        }
    }
}

// Node MLP: K=128 -> 64 (relu) -> 64. Full h[64] in regs -> x loaded once.
__global__ __launch_bounds__(256)
void node_mlp(const void* __restrict__ hin,
              const float* __restrict__ m,
              const float* __restrict__ degv,
              const int* __restrict__ Sptr,
              const int* __restrict__ gflag,
              const float* __restrict__ w1, const float* __restrict__ b1,
              const float* __restrict__ w2, const float* __restrict__ b2,
              void* __restrict__ out_f, void* __restrict__ out_b,
              int N, int ph4) {
    const int isbf = gflag[0];
    const int n = blockIdx.x * 256 + threadIdx.x;
    if (n >= N) return;
    const float scale = ph4 ? (1.0f / fmaxf(degv[n], 1.0f))
                            : (1.0f / (float)Sptr[0]);
    const size_t offH = (size_t)n * 64;
    const float* pm = m + offH;

    float h[64];
#pragma unroll
    for (int j = 0; j < 64; ++j) h[j] = b1[j];
#pragma unroll 1
    for (int kc = 0; kc < 8; ++kc) {
        float xr[16];
        if (kc < 4) {
            load16(hin, offH + kc * 16, isbf, xr);
        } else {
            load16f(pm + (kc - 4) * 16, xr);
#pragma unroll
            for (int k = 0; k < 16; ++k) xr[k] *= scale;
        }
#pragma unroll
        for (int k = 0; k < 16; ++k)
#pragma unroll
            for (int j = 0; j < 64; ++j)
                h[j] = fmaf(xr[k], w1[(kc * 16 + k) * 64 + j], h[j]);
    }
#pragma unroll
    for (int j = 0; j < 64; ++j) h[j] = fmaxf(h[j], 0.0f);

    float acc[64];
#pragma unroll
    for (int o = 0; o < 64; ++o) acc[o] = b2[o];
#pragma unroll
    for (int j = 0; j < 64; ++j)
#pragma unroll
        for (int o = 0; o < 64; ++o)
            acc[o] = fmaf(h[j], w2[j * 64 + o], acc[o]);

    if (isbf) {
        unsigned int ob[32];
#pragma unroll
        for (int i = 0; i < 32; ++i) {
            __hip_bfloat162 p2 = __float22bfloat162_rn(make_float2(acc[2 * i], acc[2 * i + 1]));
            ob[i] = *reinterpret_cast<unsigned int*>(&p2);
        }
        uint4* qo = reinterpret_cast<uint4*>((__hip_bfloat16*)out_b + offH);
#pragma unroll
        for (int i = 0; i < 8; ++i) qo[i] = make_uint4(ob[4*i], ob[4*i+1], ob[4*i+2], ob[4*i+3]);
    } else {
        float4* qf = reinterpret_cast<float4*>((float*)out_f + offH);
#pragma unroll
        for (int i = 0; i < 16; ++i) qf[i] = make_float4(acc[4*i], acc[4*i+1], acc[4*i+2], acc[4*i+3]);
    }
}

extern "C" void kernel_launch(void* const* d_in, const int* in_sizes, int n_in,
                              void* d_out, int out_size, void* d_ws, size_t ws_size,
                              hipStream_t stream) {
    const void* h_v    = d_in[0];
    const void* h_u    = d_in[1];
    const void* e_feat = d_in[2];
    const int* eidx = (const int*)d_in[3];
    const int* Sptr = (const int*)d_in[4];

    const int NV_ = in_sizes[0] / 64;
    const int NU_ = in_sizes[1] / 64;
    const int E_  = in_sizes[2] / 64;
    const int* src = eidx;        // edge_index row 0 (indexes h_v)
    const int* dst = eidx + E_;   // edge_index row 1 (indexes h_u)

    const int maxN = (NV_ > NU_) ? NV_ : NU_;
    // ws layout: flag (64B) | mbuf[maxN*64] f32 | degv[NV] f32 | wf (f32 weights) | packed bf16 frags
    int*   flag = (int*)d_ws;
    float* mbuf = (float*)((char*)d_ws + 64);
    float* degv = mbuf + (size_t)maxN * 64;
    float* wf   = degv + NV_;

    WArgs wa;
    int accum = 0;
    int maxCnt = 0;
    for (int i = 0; i < 16; ++i) {
        wa.p[i] = d_in[5 + i];
        wa.off[i] = accum;
        wa.cnt[i] = in_sizes[5 + i];
        accum += in_sizes[5 + i];
        if (in_sizes[5 + i] > maxCnt) maxCnt = in_sizes[5 + i];
    }

    // Packed fragment buffers (hi/lo bf16) after wf.
    const int W1P = 8 * 6 * 64 * 8;   // 24576
    const int W2P = 4 * 4 * 64 * 8;   // 8192
    ushort* pk = (ushort*)(wf + accum);
    ushort* p1w1hi = pk;
    ushort* p1w1lo = p1w1hi + W1P;
    ushort* p1w2hi = p1w1lo + W1P;
    ushort* p1w2lo = p1w2hi + W2P;
    ushort* p3w1hi = p1w2lo + W2P;
    ushort* p3w1lo = p3w1hi + W1P;
    ushort* p3w2hi = p3w1lo + W1P;
    ushort* p3w2lo = p3w2hi + W2P;

    detect_kernel<<<1, 512, 0, stream>>>((const unsigned int*)h_v, flag);

    dim3 cg((maxCnt + 255) / 256, 16);
    cvt_all<<<cg, 256, 0, stream>>>(wa, wf, flag);

    pack_w1<<<(W1P + 255) / 256, 256, 0, stream>>>(wf + wa.off[0], p1w1hi, p1w1lo);
    pack_w2<<<(W2P + 255) / 256, 256, 0, stream>>>(wf + wa.off[2], p1w2hi, p1w2lo);
    pack_w1<<<(W1P + 255) / 256, 256, 0, stream>>>(wf + wa.off[8], p3w1hi, p3w1lo);
    pack_w2<<<(W2P + 255) / 256, 256, 0, stream>>>(wf + wa.off[10], p3w2hi, p3w2lo);

    // Output regions per dtype interpretation.
    void* out_hv_f = d_out;
    void* out_hu_f = (void*)((float*)d_out + (size_t)NV_ * 64);
    void* out_hu_b = (void*)((__hip_bfloat16*)d_out + (size_t)NV_ * 64);

    hipMemsetAsync(mbuf, 0, (size_t)maxN * 64 * sizeof(float), stream);

    const int egrid16 = (E_ + 15) / 16;

    // phase 1: A=h_v rows(src), B=h_u rows(dst), scatter by dst
    edge_mlp_mfma<0><<<egrid16, 64, 0, stream>>>(h_v, h_u, e_feat, src, dst, flag,
        p1w1hi, p1w1lo, p1w2hi, p1w2lo,
        wf + wa.off[1], wf + wa.off[3], mbuf, E_, 0);
    edge_mlp_mfma<1><<<egrid16, 64, 0, stream>>>(h_v, h_u, e_feat, src, dst, flag,
        p1w1hi, p1w1lo, p1w2hi, p1w2lo,
        wf + wa.off[1], wf + wa.off[3], mbuf, E_, 0);

    const int ngridU = (NU_ + 255) / 256;
    node_mlp<<<ngridU, 256, 0, stream>>>(h_u, mbuf, nullptr, Sptr, flag,
        wf + wa.off[4], wf + wa.off[5], wf + wa.off[6], wf + wa.off[7],
        out_hu_f, out_hu_b, NU_, 0);

    hipMemsetAsync(mbuf, 0, (size_t)maxN * 64 * sizeof(float), stream);
    hipMemsetAsync(degv, 0, (size_t)NV_ * sizeof(float), stream);

    deg_kernel<<<(E_ + 255) / 256, 256, 0, stream>>>(src, degv, E_);

    // phase 3: A=h_u_out rows(dst), B=h_v rows(src), scatter by src
    edge_mlp_mfma<0><<<egrid16, 64, 0, stream>>>(out_hu_f, h_v, e_feat, src, dst, flag,
        p3w1hi, p3w1lo, p3w2hi, p3w2lo,
        wf + wa.off[9], wf + wa.off[11], mbuf, E_, 1);
    edge_mlp_mfma<1><<<egrid16, 64, 0, stream>>>(out_hu_b, h_v, e_feat, src, dst, flag,
        p3w1hi, p3w1lo, p3w2hi, p3w2lo,
        wf + wa.off[9], wf + wa.off[11], mbuf, E_, 1);

    const int ngridV = (NV_ + 255) / 256;
    node_mlp<<<ngridV, 256, 0, stream>>>(h_v, mbuf, degv, Sptr, flag,
        wf + wa.off[12], wf + wa.off[13], wf + wa.off[14], wf + wa.off[15],
        out_hv_f, d_out, NV_, 1);
}

// Round 6
// 767.761 us; speedup vs baseline: 2.9972x; 1.2222x over previous
//
#include <hip/hip_runtime.h>
#include <hip/hip_bf16.h>
#include <stdint.h>

// SparseMPNNLayer: bipartite MPNN, H=64. Round 7: LDS-resident weights.
//  R5 post-mortem: each 16-edge wave re-read the full 128KB packed-weight set from
//  L2 (4 GB/dispatch, same hot lines on every XCD) -> L2 hot-line bound, occupancy
//  irrelevant. This round: persistent blocks (grid=256, 512 thr = 8 waves), weights
//  staged ONCE per block into LDS (128KB), block grid-strides over 128-edge tiles
//  (16 edges/wave/tile). Weight L2 traffic 4GB -> 32MB. In-loop syncs are per-wave
//  lgkmcnt(0)+sched_barrier (H/idx are wave-private); single __syncthreads after fill.
//  Math unchanged: layer1 3-pass hi/lo split (f32 path), layer2 3-pass via LDS H.

typedef __attribute__((ext_vector_type(8))) short short8v;   // 8 bf16 (4 VGPRs)
typedef __attribute__((ext_vector_type(4))) float f32x4;

#define WSYNC() do { asm volatile("s_waitcnt lgkmcnt(0)" ::: "memory"); \
                     __builtin_amdgcn_sched_barrier(0); } while (0)

__device__ __forceinline__ ushort f2bf_rn(float f) {
    union { float f; unsigned int u; } v; v.f = f;
    unsigned int u = v.u;
    unsigned int r = u + 0x7fffu + ((u >> 16) & 1u);   // round-to-nearest-even
    return (ushort)(r >> 16);
}
__device__ __forceinline__ float bf2f(ushort h) {
    union { unsigned int u; float f; } v; v.u = ((unsigned int)h) << 16;
    return v.f;
}

__device__ __forceinline__ void unpack2(unsigned int u, float& a, float& b) {
    union { unsigned int i; float f; } x, y;
    x.i = u << 16;
    y.i = u & 0xffff0000u;
    a = x.f; b = y.f;
}

__device__ __forceinline__ void load16bf(const __hip_bfloat16* __restrict__ p, float* xr) {
    const uint4* q = reinterpret_cast<const uint4*>(p);
    uint4 a = q[0];
    uint4 b = q[1];
    unpack2(a.x, xr[0], xr[1]);  unpack2(a.y, xr[2], xr[3]);
    unpack2(a.z, xr[4], xr[5]);  unpack2(a.w, xr[6], xr[7]);
    unpack2(b.x, xr[8], xr[9]);  unpack2(b.y, xr[10], xr[11]);
    unpack2(b.z, xr[12], xr[13]); unpack2(b.w, xr[14], xr[15]);
}

__device__ __forceinline__ void load16f(const float* __restrict__ p, float* xr) {
    const float4* q = reinterpret_cast<const float4*>(p);
#pragma unroll
    for (int i = 0; i < 4; ++i) {
        float4 v = q[i];
        xr[4*i+0] = v.x; xr[4*i+1] = v.y; xr[4*i+2] = v.z; xr[4*i+3] = v.w;
    }
}

__device__ __forceinline__ void load16(const void* base, size_t off, int isbf, float* xr) {
    if (isbf) load16bf((const __hip_bfloat16*)base + off, xr);
    else      load16f((const float*)base + off, xr);
}

__device__ __forceinline__ void ld8f(const float* __restrict__ p, float* t) {
    float4 a = *(const float4*)p;
    float4 b = *(const float4*)(p + 4);
    t[0]=a.x; t[1]=a.y; t[2]=a.z; t[3]=a.w;
    t[4]=b.x; t[5]=b.y; t[6]=b.z; t[7]=b.w;
}

// Split 8 f32 into hi/lo bf16 fragments (RNE both planes).
__device__ __forceinline__ void cvt8(const float* __restrict__ t, short8v& hi, short8v& lo) {
#pragma unroll
    for (int j = 0; j < 8; ++j) {
        ushort h = f2bf_rn(t[j]);
        hi[j] = (short)h;
        lo[j] = (short)f2bf_rn(t[j] - bf2f(h));
    }
}

// Classify storage of h_v (bf16-packed vs f32) by exponent-field statistics.
__global__ void detect_kernel(const unsigned int* __restrict__ hv, int* __restrict__ flag) {
    __shared__ int cnt;
    if (threadIdx.x == 0) cnt = 0;
    __syncthreads();
    unsigned int w = hv[threadIdx.x];
    int ef = (w >> 7) & 0xff;
    if (ef >= 100 && ef <= 140) atomicAdd(&cnt, 1);
    __syncthreads();
    if (threadIdx.x == 0) flag[0] = (cnt > 256) ? 1 : 0;
}

struct WArgs {
    const void* p[16];
    int off[16];
    int cnt[16];
};

__global__ void cvt_all(WArgs wa, float* __restrict__ wf, const int* __restrict__ gflag) {
    const int isbf = gflag[0];
    const int t = blockIdx.y;
    const int i = blockIdx.x * 256 + threadIdx.x;
    if (i >= wa.cnt[t]) return;
    wf[wa.off[t] + i] = isbf ? __bfloat162float(((const __hip_bfloat16*)wa.p[t])[i])
                             : ((const float*)wa.p[t])[i];
}

// Pack W1 (f32 192x128) into MFMA B-fragment order for 16x16x32, split hi/lo bf16.
// Layout: [nt(8)][kt(6)][lane(64)][j(8)]; element = w1[(kt*32 + (lane>>4)*8 + j)*128 + nt*16 + (lane&15)]
__global__ void pack_w1(const float* __restrict__ w1, ushort* __restrict__ hi, ushort* __restrict__ lo) {
    int i = blockIdx.x * 256 + threadIdx.x;
    if (i >= 8 * 6 * 64 * 8) return;
    int j = i & 7;
    int lane = (i >> 3) & 63;
    int t = i >> 9;
    int kt = t % 6, nt = t / 6;
    float w = w1[(kt * 32 + (lane >> 4) * 8 + j) * 128 + nt * 16 + (lane & 15)];
    ushort h = f2bf_rn(w);
    hi[i] = h;
    lo[i] = f2bf_rn(w - bf2f(h));
}

// Pack W2^T (from w2 f32 128x64) into MFMA A-fragment order for 16x16x32, split hi/lo.
// Layout: [pair(4)][ot(4)][lane(64)][j(8)]; element = w2[(pair*32 + (lane>>4)*8 + j)*64 + ot*16 + (lane&15)]
__global__ void pack_w2(const float* __restrict__ w2, ushort* __restrict__ hi, ushort* __restrict__ lo) {
    int i = blockIdx.x * 256 + threadIdx.x;
    if (i >= 4 * 4 * 64 * 8) return;
    int j = i & 7;
    int lane = (i >> 3) & 63;
    int t = i >> 9;
    int ot = t & 3, pair = t >> 2;
    float w = w2[(pair * 32 + (lane >> 4) * 8 + j) * 64 + ot * 16 + (lane & 15)];
    ushort h = f2bf_rn(w);
    hi[i] = h;
    lo[i] = f2bf_rn(w - bf2f(h));
}

__global__ void deg_kernel(const int* __restrict__ src, float* __restrict__ degv, int E) {
    int e = blockIdx.x * 256 + threadIdx.x;
    if (e < E) atomicAdd(&degv[src[e]], 1.0f);
}

// ---------------- persistent MFMA edge MLP, weights in LDS ----------------
// grid=256 blocks x 512 threads (8 waves). Each wave: 16 edges per tile,
// block strides over 128-edge tiles. Weights (hi/lo planes, 128KB) filled
// into LDS once per block.
// ph3==0: A=h_v rows idx src, B=h_u rows idx dst, scatter row = dst
// ph3==1: A=h_u_out rows idx dst, B=h_v rows idx src, scatter row = src
template <int ISBF>
__global__ __launch_bounds__(512, 1)
void edge_mlp_mfma(const void* __restrict__ A_, const void* __restrict__ B_,
                   const void* __restrict__ E_,
                   const int* __restrict__ src_idx, const int* __restrict__ dst_idx,
                   const int* __restrict__ gflag,
                   const ushort* __restrict__ w1hi, const ushort* __restrict__ w1lo,
                   const ushort* __restrict__ w2hi, const ushort* __restrict__ w2lo,
                   const float* __restrict__ b1, const float* __restrict__ b2,
                   float* __restrict__ accum, int E, int ph3) {
    if (gflag[0] != ISBF) return;

    // LDS pool: w1hi 49152B | w1lo 49152B | w2hi 16384B | w2lo 16384B |
    //           hstage 8x(2x16x40 ushort)=20480B | idx 8x48 int=1536B  => 153088B
    __shared__ __align__(16) char smem[153088];
    ushort* sw1h = (ushort*)smem;
    ushort* sw1l = sw1h + 24576;
    ushort* sw2h = sw1l + 24576;
    ushort* sw2l = sw2h + 8192;
    ushort* shb  = sw2l + 8192;           // 10240 ushorts
    int*    sidx = (int*)(shb + 10240);   // 384 ints

    const int tid = threadIdx.x;
    // Cooperative one-time weight fill (sources are L2-hot packed buffers).
    {
        const uint4* g1h = (const uint4*)w1hi;
        const uint4* g1l = (const uint4*)w1lo;
        const uint4* g2h = (const uint4*)w2hi;
        const uint4* g2l = (const uint4*)w2lo;
        uint4* d1h = (uint4*)sw1h;
        uint4* d1l = (uint4*)sw1l;
        uint4* d2h = (uint4*)sw2h;
        uint4* d2l = (uint4*)sw2l;
        for (int i = tid; i < 3072; i += 512) d1h[i] = g1h[i];
        for (int i = tid; i < 3072; i += 512) d1l[i] = g1l[i];
        for (int i = tid; i < 1024; i += 512) d2h[i] = g2h[i];
        for (int i = tid; i < 1024; i += 512) d2l[i] = g2l[i];
    }
    __syncthreads();

    const int wid  = tid >> 6;
    const int lane = tid & 63;
    const int eloc = lane & 15;            // edge-col lane index
    const int khalf = (lane >> 4) * 8;     // K-slice base within a K=32 tile
    ushort* hw_hi = shb + wid * 1280;      // per-wave H staging, row stride 40 ushorts
    ushort* hw_lo = hw_hi + 640;
    float*  smt   = (float*)hw_hi;         // epilogue overlay (16x17 f32, 1088B)
    int* rowS = sidx + wid * 48;
    int* gA   = rowS + 16;
    int* gB   = rowS + 32;

    // Biases preloaded once per wave (held across all tiles).
    float b1v[8];
    float b2r[4][4];
#pragma unroll
    for (int nt = 0; nt < 8; ++nt) b1v[nt] = b1[nt * 16 + eloc];
#pragma unroll
    for (int ot = 0; ot < 4; ++ot)
#pragma unroll
        for (int r = 0; r < 4; ++r) b2r[ot][r] = b2[ot * 16 + (lane >> 4) * 4 + r];

    const int ntile = (E + 127) >> 7;
    for (int t = blockIdx.x; t < ntile; t += gridDim.x) {
        const int ebase = t * 128 + wid * 16;
        const int cnt = min(16, E - ebase);
        if (cnt <= 0) continue;

        if (lane < 16) {
            int e = ebase + ((lane < cnt) ? lane : (cnt - 1));
            int s = src_idx[e], d = dst_idx[e];
            rowS[lane] = ph3 ? s : d;
            gA[lane]   = ph3 ? d : s;
            gB[lane]   = ph3 ? s : d;
        }
        WSYNC();

        // Gather + split this wave's 16 edge rows into A-fragments.
        short8v ah[6], al[6];
        {
            const int elc = (eloc < cnt) ? eloc : (cnt - 1);
            if (ISBF) {
                const ushort* ra = (const ushort*)A_ + (size_t)gA[elc] * 64;
                const ushort* rb = (const ushort*)B_ + (size_t)gB[elc] * 64;
                const ushort* re = (const ushort*)E_ + (size_t)(ebase + elc) * 64;
                ah[0] = *(const short8v*)(ra + khalf);
                ah[1] = *(const short8v*)(ra + 32 + khalf);
                ah[2] = *(const short8v*)(rb + khalf);
                ah[3] = *(const short8v*)(rb + 32 + khalf);
                ah[4] = *(const short8v*)(re + khalf);
                ah[5] = *(const short8v*)(re + 32 + khalf);
            } else {
                const float* ra = (const float*)A_ + (size_t)gA[elc] * 64;
                const float* rb = (const float*)B_ + (size_t)gB[elc] * 64;
                const float* re = (const float*)E_ + (size_t)(ebase + elc) * 64;
                float tt[8];
                ld8f(ra + khalf, tt);      cvt8(tt, ah[0], al[0]);
                ld8f(ra + 32 + khalf, tt); cvt8(tt, ah[1], al[1]);
                ld8f(rb + khalf, tt);      cvt8(tt, ah[2], al[2]);
                ld8f(rb + 32 + khalf, tt); cvt8(tt, ah[3], al[3]);
                ld8f(re + khalf, tt);      cvt8(tt, ah[4], al[4]);
                ld8f(re + 32 + khalf, tt); cvt8(tt, ah[5], al[5]);
            }
        }

        f32x4 acc2[4];
#pragma unroll
        for (int ot = 0; ot < 4; ++ot)
#pragma unroll
            for (int r = 0; r < 4; ++r) acc2[ot][r] = b2r[ot][r];

#pragma unroll 1
        for (int pair = 0; pair < 4; ++pair) {           // 32 hidden per pair
#pragma unroll
            for (int nt2 = 0; nt2 < 2; ++nt2) {          // 16 hidden per ntile
                const int nt = pair * 2 + nt2;
                const float bv = b1v[nt];
                f32x4 c1;
                c1[0] = bv; c1[1] = bv; c1[2] = bv; c1[3] = bv;
#pragma unroll
                for (int kt = 0; kt < 6; ++kt) {
                    const int wo = ((nt * 6 + kt) * 64 + lane) * 8;
                    const short8v bh = *(const short8v*)(sw1h + wo);
                    const short8v bl = *(const short8v*)(sw1l + wo);
                    c1 = __builtin_amdgcn_mfma_f32_16x16x32_bf16(ah[kt], bh, c1, 0, 0, 0);
                    c1 = __builtin_amdgcn_mfma_f32_16x16x32_bf16(ah[kt], bl, c1, 0, 0, 0);
                    if (!ISBF)
                        c1 = __builtin_amdgcn_mfma_f32_16x16x32_bf16(al[kt], bh, c1, 0, 0, 0);
                }
                // relu + split f32 -> hi/lo bf16 into per-wave H staging
                // (C layout: col=lane&15=hidden, row=(lane>>4)*4+r=edge)
#pragma unroll
                for (int r = 0; r < 4; ++r) {
                    float v = fmaxf(c1[r], 0.0f);
                    ushort h = f2bf_rn(v);
                    ushort l = f2bf_rn(v - bf2f(h));
                    const int er = (lane >> 4) * 4 + r;
                    hw_hi[er * 40 + nt2 * 16 + eloc] = h;
                    hw_lo[er * 40 + nt2 * 16 + eloc] = l;
                }
            }
            WSYNC();   // H writes visible to this wave's cross-lane reads
            {
                const short8v bh = *(const short8v*)(hw_hi + eloc * 40 + khalf);
                const short8v bl = *(const short8v*)(hw_lo + eloc * 40 + khalf);
                WSYNC();   // reads landed before MFMA use / before next-pair overwrites
#pragma unroll
                for (int ot = 0; ot < 4; ++ot) {
                    const int wo = ((pair * 4 + ot) * 64 + lane) * 8;
                    const short8v wh = *(const short8v*)(sw2h + wo);
                    const short8v wl = *(const short8v*)(sw2l + wo);
                    acc2[ot] = __builtin_amdgcn_mfma_f32_16x16x32_bf16(wh, bh, acc2[ot], 0, 0, 0);
                    acc2[ot] = __builtin_amdgcn_mfma_f32_16x16x32_bf16(wh, bl, acc2[ot], 0, 0, 0);
                    acc2[ot] = __builtin_amdgcn_mfma_f32_16x16x32_bf16(wl, bh, acc2[ot], 0, 0, 0);
                }
            }
        }

        // Epilogue: per-wave transpose via smt overlay -> coalesced row atomics.
#pragma unroll 1
        for (int ot = 0; ot < 4; ++ot) {
            WSYNC();   // previous smt readers (or H readers) drained
#pragma unroll
            for (int r = 0; r < 4; ++r)
                smt[eloc * 17 + (lane >> 4) * 4 + r] = acc2[ot][r];
            WSYNC();
#pragma unroll 1
            for (int i = 0; i < 16; i += 4) {
                const int e = i + (lane >> 4);
                if (e < cnt)
                    atomicAdd(&accum[(size_t)rowS[e] * 64 + ot * 16 + eloc],
                              smt[e * 17 + eloc]);
            }
        }
    }
}

// Node MLP: K=128 -> 64 (relu) -> 64. Full h[64] in regs -> x loaded once.
__global__ __launch_bounds__(256)
void node_mlp(const void* __restrict__ hin,
              const float* __restrict__ m,
              const float* __restrict__ degv,
              const int* __restrict__ Sptr,
              const int* __restrict__ gflag,
              const float* __restrict__ w1, const float* __restrict__ b1,
              const float* __restrict__ w2, const float* __restrict__ b2,
              void* __restrict__ out_f, void* __restrict__ out_b,
              int N, int ph4) {
    const int isbf = gflag[0];
    const int n = blockIdx.x * 256 + threadIdx.x;
    if (n >= N) return;
    const float scale = ph4 ? (1.0f / fmaxf(degv[n], 1.0f))
                            : (1.0f / (float)Sptr[0]);
    const size_t offH = (size_t)n * 64;
    const float* pm = m + offH;

    float h[64];
#pragma unroll
    for (int j = 0; j < 64; ++j) h[j] = b1[j];
#pragma unroll 1
    for (int kc = 0; kc < 8; ++kc) {
        float xr[16];
        if (kc < 4) {
            load16(hin, offH + kc * 16, isbf, xr);
        } else {
            load16f(pm + (kc - 4) * 16, xr);
#pragma unroll
            for (int k = 0; k < 16; ++k) xr[k] *= scale;
        }
#pragma unroll
        for (int k = 0; k < 16; ++k)
#pragma unroll
            for (int j = 0; j < 64; ++j)
                h[j] = fmaf(xr[k], w1[(kc * 16 + k) * 64 + j], h[j]);
    }
#pragma unroll
    for (int j = 0; j < 64; ++j) h[j] = fmaxf(h[j], 0.0f);

    float acc[64];
#pragma unroll
    for (int o = 0; o < 64; ++o) acc[o] = b2[o];
#pragma unroll
    for (int j = 0; j < 64; ++j)
#pragma unroll
        for (int o = 0; o < 64; ++o)
            acc[o] = fmaf(h[j], w2[j * 64 + o], acc[o]);

    if (isbf) {
        unsigned int ob[32];
#pragma unroll
        for (int i = 0; i < 32; ++i) {
            __hip_bfloat162 p2 = __float22bfloat162_rn(make_float2(acc[2 * i], acc[2 * i + 1]));
            ob[i] = *reinterpret_cast<unsigned int*>(&p2);
        }
        uint4* qo = reinterpret_cast<uint4*>((__hip_bfloat16*)out_b + offH);
#pragma unroll
        for (int i = 0; i < 8; ++i) qo[i] = make_uint4(ob[4*i], ob[4*i+1], ob[4*i+2], ob[4*i+3]);
    } else {
        float4* qf = reinterpret_cast<float4*>((float*)out_f + offH);
#pragma unroll
        for (int i = 0; i < 16; ++i) qf[i] = make_float4(acc[4*i], acc[4*i+1], acc[4*i+2], acc[4*i+3]);
    }
}

extern "C" void kernel_launch(void* const* d_in, const int* in_sizes, int n_in,
                              void* d_out, int out_size, void* d_ws, size_t ws_size,
                              hipStream_t stream) {
    const void* h_v    = d_in[0];
    const void* h_u    = d_in[1];
    const void* e_feat = d_in[2];
    const int* eidx = (const int*)d_in[3];
    const int* Sptr = (const int*)d_in[4];

    const int NV_ = in_sizes[0] / 64;
    const int NU_ = in_sizes[1] / 64;
    const int E_  = in_sizes[2] / 64;
    const int* src = eidx;        // edge_index row 0 (indexes h_v)
    const int* dst = eidx + E_;   // edge_index row 1 (indexes h_u)

    const int maxN = (NV_ > NU_) ? NV_ : NU_;
    // ws layout: flag (64B) | mbuf[maxN*64] f32 | degv[NV] f32 | wf (f32 weights) | packed bf16 frags
    int*   flag = (int*)d_ws;
    float* mbuf = (float*)((char*)d_ws + 64);
    float* degv = mbuf + (size_t)maxN * 64;
    float* wf   = degv + NV_;

    WArgs wa;
    int accum = 0;
    int maxCnt = 0;
    for (int i = 0; i < 16; ++i) {
        wa.p[i] = d_in[5 + i];
        wa.off[i] = accum;
        wa.cnt[i] = in_sizes[5 + i];
        accum += in_sizes[5 + i];
        if (in_sizes[5 + i] > maxCnt) maxCnt = in_sizes[5 + i];
    }

    // Packed fragment buffers (hi/lo bf16) after wf.
    const int W1P = 8 * 6 * 64 * 8;   // 24576
    const int W2P = 4 * 4 * 64 * 8;   // 8192
    ushort* pk = (ushort*)(wf + accum);
    ushort* p1w1hi = pk;
    ushort* p1w1lo = p1w1hi + W1P;
    ushort* p1w2hi = p1w1lo + W1P;
    ushort* p1w2lo = p1w2hi + W2P;
    ushort* p3w1hi = p1w2lo + W2P;
    ushort* p3w1lo = p3w1hi + W1P;
    ushort* p3w2hi = p3w1lo + W1P;
    ushort* p3w2lo = p3w2hi + W2P;

    detect_kernel<<<1, 512, 0, stream>>>((const unsigned int*)h_v, flag);

    dim3 cg((maxCnt + 255) / 256, 16);
    cvt_all<<<cg, 256, 0, stream>>>(wa, wf, flag);

    pack_w1<<<(W1P + 255) / 256, 256, 0, stream>>>(wf + wa.off[0], p1w1hi, p1w1lo);
    pack_w2<<<(W2P + 255) / 256, 256, 0, stream>>>(wf + wa.off[2], p1w2hi, p1w2lo);
    pack_w1<<<(W1P + 255) / 256, 256, 0, stream>>>(wf + wa.off[8], p3w1hi, p3w1lo);
    pack_w2<<<(W2P + 255) / 256, 256, 0, stream>>>(wf + wa.off[10], p3w2hi, p3w2lo);

    // Output regions per dtype interpretation.
    void* out_hv_f = d_out;
    void* out_hu_f = (void*)((float*)d_out + (size_t)NV_ * 64);
    void* out_hu_b = (void*)((__hip_bfloat16*)d_out + (size_t)NV_ * 64);

    hipMemsetAsync(mbuf, 0, (size_t)maxN * 64 * sizeof(float), stream);

    const int EG = 256;   // persistent blocks, 1/CU (LDS-bound)

    // phase 1: A=h_v rows(src), B=h_u rows(dst), scatter by dst
    edge_mlp_mfma<0><<<EG, 512, 0, stream>>>(h_v, h_u, e_feat, src, dst, flag,
        p1w1hi, p1w1lo, p1w2hi, p1w2lo,
        wf + wa.off[1], wf + wa.off[3], mbuf, E_, 0);
    edge_mlp_mfma<1><<<EG, 512, 0, stream>>>(h_v, h_u, e_feat, src, dst, flag,
        p1w1hi, p1w1lo, p1w2hi, p1w2lo,
        wf + wa.off[1], wf + wa.off[3], mbuf, E_, 0);

    const int ngridU = (NU_ + 255) / 256;
    node_mlp<<<ngridU, 256, 0, stream>>>(h_u, mbuf, nullptr, Sptr, flag,
        wf + wa.off[4], wf + wa.off[5], wf + wa.off[6], wf + wa.off[7],
        out_hu_f, out_hu_b, NU_, 0);

    hipMemsetAsync(mbuf, 0, (size_t)maxN * 64 * sizeof(float), stream);
    hipMemsetAsync(degv, 0, (size_t)NV_ * sizeof(float), stream);

    deg_kernel<<<(E_ + 255) / 256, 256, 0, stream>>>(src, degv, E_);

    // phase 3: A=h_u_out rows(dst), B=h_v rows(src), scatter by src
    edge_mlp_mfma<0><<<EG, 512, 0, stream>>>(out_hu_f, h_v, e_feat, src, dst, flag,
        p3w1hi, p3w1lo, p3w2hi, p3w2lo,
        wf + wa.off[9], wf + wa.off[11], mbuf, E_, 1);
    edge_mlp_mfma<1><<<EG, 512, 0, stream>>>(out_hu_b, h_v, e_feat, src, dst, flag,
        p3w1hi, p3w1lo, p3w2hi, p3w2lo,
        wf + wa.off[9], wf + wa.off[11], mbuf, E_, 1);

    const int ngridV = (NV_ + 255) / 256;
    node_mlp<<<ngridV, 256, 0, stream>>>(h_v, mbuf, degv, Sptr, flag,
        wf + wa.off[12], wf + wa.off[13], wf + wa.off[14], wf + wa.off[15],
        out_hv_f, d_out, NV_, 1);
}